// Round 6
// baseline (1835.622 us; speedup 1.0000x reference)
//
#include <hip/hip_runtime.h>

// Problem: B=2, N=128, C=256, H=8, D=32.
// Established: inputs fp32 (R1 bf16-read NaN'd; fp32 path finite).
// R6 hypothesis: OUTPUT is fp32 (reference dtype), not bf16 — R3-R5's
// decorrelated-but-same-scale error matches u16-written/fp32-read aliasing.
// Pipeline = R5's layout-trivial VALU version, only the final store changed.
typedef unsigned short u16;

#define SCALE 0.17677669529663687f  // 32^-0.5

__device__ __forceinline__ float us2f(u16 u){ return __uint_as_float(((unsigned int)u)<<16); }
__device__ __forceinline__ u16 f2us(float f){
  unsigned int x = __float_as_uint(f);
  x += 0x7fffu + ((x>>16)&1u);   // RNE
  return (u16)(x>>16);
}
// flag-selected input read: is32 ? fp32 : bf16
__device__ __forceinline__ float ldin(const void* p, int i, int is32){
  return is32 ? ((const float*)p)[i] : us2f(((const u16*)p)[i]);
}

// ---------------- dtype sniffer (EVEN u16 indices of e) ----------------
__global__ void sniff_kernel(const u16* __restrict__ e, int* __restrict__ flag){
  __shared__ int partial[4];
  int t = threadIdx.x;
  int cnt = 0;
  for (int i = t; i < 4096; i += 256){
    u16 u = e[2*i];                  // EVEN half: fp32 -> low mantissa bits
    int ex = (u >> 7) & 0xFF;
    cnt += (ex >= 118 && ex <= 132) ? 1 : 0;
  }
  #pragma unroll
  for (int off=32; off>=1; off>>=1) cnt += __shfl_xor(cnt, off);
  if ((t&63)==0) partial[t>>6] = cnt;
  __syncthreads();
  if (t==0){
    int tot = partial[0]+partial[1]+partial[2]+partial[3];
    *flag = (tot < 2048) ? 1 : 0;   // 1 => inputs are fp32
  }
}

// ---------------- LayerNorm: one wave per token (256 ch) ----------------
__global__ __launch_bounds__(256) void ln_kernel(const void* __restrict__ e, const void* __restrict__ g,
                                                 const void* __restrict__ bb, u16* __restrict__ eln,
                                                 const int* __restrict__ flagp){
  int is32 = *flagp;
  int t = threadIdx.x;
  int tok = blockIdx.x*4 + (t>>6);
  int lane = t & 63;
  int c0 = lane*4;
  float x[4];
  #pragma unroll
  for (int q=0;q<4;++q) x[q] = ldin(e, tok*256 + c0 + q, is32);
  float sum = x[0]+x[1]+x[2]+x[3];
  float sq  = x[0]*x[0] + x[1]*x[1] + x[2]*x[2] + x[3]*x[3];
  #pragma unroll
  for (int off=32; off>=1; off>>=1){ sum += __shfl_xor(sum, off); sq += __shfl_xor(sq, off); }
  float mu = sum * 0.00390625f;
  float var = sq * 0.00390625f - mu*mu;
  float rstd = rsqrtf(var + 1e-5f);
  #pragma unroll
  for (int q=0;q<4;++q){
    float gv = ldin(g, c0+q, is32), bv = ldin(bb, c0+q, is32);
    eln[tok*256 + c0 + q] = f2us((x[q]-mu)*rstd*gv + bv);
  }
}

// ---------------- QKV (+E) GEMM, VALU: 4 tokens/block, thread = column ----------------
__global__ __launch_bounds__(256) void qkv_valu(const u16* __restrict__ eln, const void* __restrict__ W,
    const void* __restrict__ WE, const void* __restrict__ bqkv, const void* __restrict__ bE,
    u16* __restrict__ Qb, u16* __restrict__ Kb, u16* __restrict__ Vb, float* __restrict__ Eb,
    const int* __restrict__ flagp){
  int is32 = *flagp;
  __shared__ float As[4][256];
  int tok0 = blockIdx.x*4;
  int t = threadIdx.x;
  for (int i=t; i<1024; i+=256){
    int tokL = i>>8, k = i&255;
    As[tokL][k] = us2f(eln[(tok0+tokL)*256 + k]);
  }
  __syncthreads();
  float acc[4][3] = {};
  for (int k=0;k<256;++k){
    float w0 = ldin(W, k*768 + t,       is32);
    float w1 = ldin(W, k*768 + t + 256, is32);
    float w2 = ldin(W, k*768 + t + 512, is32);
    #pragma unroll
    for (int i=0;i<4;++i){
      float a = As[i][k];
      acc[i][0] += a*w0; acc[i][1] += a*w1; acc[i][2] += a*w2;
    }
  }
  float bq = ldin(bqkv, t, is32), bk = ldin(bqkv, t+256, is32), bv = ldin(bqkv, t+512, is32);
  int off0 = (t&7)*32 + (t>>3);   // [tok][h][d] layout, col c = d*8+h
  #pragma unroll
  for (int i=0;i<4;++i){
    int tok = tok0+i;
    Qb[tok*256 + off0] = f2us((acc[i][0]+bq)*SCALE);
    Kb[tok*256 + off0] = f2us(acc[i][1]+bk);
    Vb[tok*256 + off0] = f2us(acc[i][2]+bv);
  }
  if (t < 32){
    int tokL = t>>3, hh = t&7;
    float s = 0.f;
    for (int k=0;k<256;++k) s += As[tokL][k]*ldin(WE, k*8+hh, is32);
    Eb[(tok0+tokL)*8+hh] = s + ldin(bE, hh, is32);
  }
}

// ---------------- Attention: one block per (b,j,h); 128x128x32 with bias softmax ----------------
__global__ __launch_bounds__(256) void attn_kernel(const u16* __restrict__ Qb, const u16* __restrict__ Kb,
    const u16* __restrict__ Vb, const float* __restrict__ Eb, const void* __restrict__ mask,
    u16* __restrict__ Va, int pass, const int* __restrict__ flagp){
  int is32 = *flagp;
  __shared__ float Qs[128][36];   // stride 36 -> conflict-free float4 reads
  __shared__ float Ks[128][36];
  __shared__ float Vs[128][36];
  int t = threadIdx.x;
  int bx = blockIdx.x;
  int h = bx & 7, j = (bx>>3) & 127, b = bx >> 10;
  {
    int row = t >> 1, seg = (t & 1)*16;
    int qoff = ((b*128 + row)*128 + j)*256 + h*32 + seg;
    int kvoff = (pass == 0) ? (((b*128 + j)*128 + row)*256 + h*32 + seg) : qoff;
    const ushort4* qp = (const ushort4*)(Qb + qoff);
    const ushort4* kp = (const ushort4*)(Kb + kvoff);
    const ushort4* vp = (const ushort4*)(Vb + kvoff);
    #pragma unroll
    for (int q2=0; q2<4; ++q2){
      ushort4 uq = qp[q2], uk = kp[q2], uv = vp[q2];
      int dd = seg + q2*4;
      Qs[row][dd+0]=us2f(uq.x); Qs[row][dd+1]=us2f(uq.y); Qs[row][dd+2]=us2f(uq.z); Qs[row][dd+3]=us2f(uq.w);
      Ks[row][dd+0]=us2f(uk.x); Ks[row][dd+1]=us2f(uk.y); Ks[row][dd+2]=us2f(uk.z); Ks[row][dd+3]=us2f(uk.w);
      Vs[row][dd+0]=us2f(uv.x); Vs[row][dd+1]=us2f(uv.y); Vs[row][dd+2]=us2f(uv.z); Vs[row][dd+3]=us2f(uv.w);
    }
  }
  __syncthreads();
  int rg = t>>3, ks = t&7;   // rows i = rg+32r (r<4), keys k = kk*8+ks (kk<16)
  float s[4][16];
  #pragma unroll
  for (int r=0;r<4;++r){
    int i = rg + 32*r;
    #pragma unroll
    for (int kk=0;kk<16;++kk){
      int k = kk*8+ks;
      int bidx = (pass==0) ? (((b*128+i)*128+k)*8+h) : (((b*128+k)*128+i)*8+h);
      s[r][kk] = Eb[bidx] + ldin(mask, bidx, is32);
    }
  }
  #pragma unroll
  for (int d4=0; d4<8; ++d4){
    float4 qv[4];
    #pragma unroll
    for (int r=0;r<4;++r) qv[r] = *(const float4*)&Qs[rg+32*r][d4*4];
    #pragma unroll
    for (int kk=0;kk<16;++kk){
      float4 kv = *(const float4*)&Ks[kk*8+ks][d4*4];
      #pragma unroll
      for (int r=0;r<4;++r)
        s[r][kk] += qv[r].x*kv.x + qv[r].y*kv.y + qv[r].z*kv.z + qv[r].w*kv.w;
    }
  }
  // sanitize non-finite scores (diagnostic guard)
  #pragma unroll
  for (int r=0;r<4;++r)
    #pragma unroll
    for (int kk=0;kk<16;++kk){
      float sv = s[r][kk];
      s[r][kk] = (sv == sv && sv < 1e30f && sv > -1e30f) ? sv : -1e30f;
    }
  float inv[4];
  #pragma unroll
  for (int r=0;r<4;++r){
    float m = s[r][0];
    #pragma unroll
    for (int kk=1;kk<16;++kk) m = fmaxf(m, s[r][kk]);
    m = fmaxf(m, __shfl_xor(m,1)); m = fmaxf(m, __shfl_xor(m,2)); m = fmaxf(m, __shfl_xor(m,4));
    float l = 0.f;
    #pragma unroll
    for (int kk=0;kk<16;++kk){ float p = __expf(s[r][kk]-m); s[r][kk]=p; l += p; }
    l += __shfl_xor(l,1); l += __shfl_xor(l,2); l += __shfl_xor(l,4);
    inv[r] = 1.0f / l;
  }
  #pragma unroll
  for (int db=0; db<2; ++db){
    float acc[4][16];
    #pragma unroll
    for (int r=0;r<4;++r)
      #pragma unroll
      for (int e2=0;e2<16;++e2) acc[r][e2] = 0.f;
    #pragma unroll
    for (int kk=0;kk<16;++kk){
      const float4* vp = (const float4*)&Vs[kk*8+ks][db*16];
      float4 v0 = vp[0], v1 = vp[1], v2 = vp[2], v3 = vp[3];
      float vb[16] = {v0.x,v0.y,v0.z,v0.w, v1.x,v1.y,v1.z,v1.w,
                      v2.x,v2.y,v2.z,v2.w, v3.x,v3.y,v3.z,v3.w};
      #pragma unroll
      for (int r=0;r<4;++r){
        float p = s[r][kk];
        #pragma unroll
        for (int e2=0;e2<16;++e2) acc[r][e2] += p * vb[e2];
      }
    }
    #pragma unroll
    for (int r=0;r<4;++r){
      int i = rg + 32*r;
      // ref concat: channel = d*16 + pass*8 + h  (concat along h axis)
      int obase = ((b*128 + i)*128 + j)*512 + pass*8 + h;
      #pragma unroll
      for (int e2=0;e2<16;++e2){
        float v = acc[r][e2] * inv[r];
        v += __shfl_xor(v,1); v += __shfl_xor(v,2); v += __shfl_xor(v,4);
        if (ks == 0) Va[obase + (db*16+e2)*16] = f2us(v);  // d = db*16+e2
      }
    }
  }
}

// ---------------- Output GEMM, VALU: 4 tokens/block, thread = output column ----------------
// R6 change: store FP32 (reference output dtype).
__global__ __launch_bounds__(256) void out_valu(const u16* __restrict__ Va, const void* __restrict__ WO,
                                                const void* __restrict__ bO, float* __restrict__ out,
                                                const int* __restrict__ flagp){
  int is32 = *flagp;
  __shared__ float As[4][512];
  int tok0 = blockIdx.x*4;
  int t = threadIdx.x;
  for (int i = t; i < 2048; i += 256){
    int tokL = i >> 9, k = i & 511;
    As[tokL][k] = us2f(Va[(tok0+tokL)*512 + k]);
  }
  __syncthreads();
  float acc[4] = {0.f,0.f,0.f,0.f};
  for (int k=0;k<512;++k){
    float w = ldin(WO, k*256 + t, is32);
    acc[0] += As[0][k]*w; acc[1] += As[1][k]*w; acc[2] += As[2][k]*w; acc[3] += As[3][k]*w;
  }
  float bias = ldin(bO, t, is32);
  #pragma unroll
  for (int i=0;i<4;++i) out[(tok0+i)*256 + t] = acc[i] + bias;
}

// ---------------- launch ----------------
// ws layout (bytes):
#define OFF_ELN 0u            // 32768*256 bf16 = 16,777,216
#define OFF_QB  16777216u
#define OFF_KB  33554432u
#define OFF_VB  50331648u
#define OFF_VA  67108864u     // 32768*512 bf16 = 33,554,432
#define OFF_EB  100663296u    // 32768*8 f32 = 1,048,576
#define OFF_FLAG 102400000u   // 4 bytes

extern "C" void kernel_launch(void* const* d_in, const int* in_sizes, int n_in,
                              void* d_out, int out_size, void* d_ws, size_t ws_size,
                              hipStream_t stream) {
  (void)in_sizes; (void)n_in; (void)out_size; (void)ws_size;
  const void* e        = d_in[0];
  const void* mask     = d_in[1];
  const void* ln_g     = d_in[2];
  const void* ln_b     = d_in[3];
  const void* W_qkv_in = d_in[4];
  const void* b_qkv_in = d_in[5];
  const void* W_E_in   = d_in[6];
  const void* b_E_in   = d_in[7];
  const void* W_qkv_out= d_in[8];
  const void* b_qkv_out= d_in[9];
  const void* W_E_out  = d_in[10];
  const void* b_E_out  = d_in[11];
  const void* W_O      = d_in[12];
  const void* b_O      = d_in[13];

  char* ws = (char*)d_ws;
  u16*  eln = (u16*)(ws + OFF_ELN);
  u16*  Qb  = (u16*)(ws + OFF_QB);
  u16*  Kb  = (u16*)(ws + OFF_KB);
  u16*  Vb  = (u16*)(ws + OFF_VB);
  u16*  Va  = (u16*)(ws + OFF_VA);
  float* Eb = (float*)(ws + OFF_EB);
  int*  flag = (int*)(ws + OFF_FLAG);

  float* out = (float*)d_out;   // fp32 output (reference dtype)

  hipLaunchKernelGGL(sniff_kernel, dim3(1), dim3(256), 0, stream, (const u16*)e, flag);
  hipLaunchKernelGGL(ln_kernel, dim3(8192), dim3(256), 0, stream, e, ln_g, ln_b, eln, flag);

  // in pass
  hipLaunchKernelGGL(qkv_valu, dim3(8192), dim3(256), 0, stream, eln, W_qkv_in, W_E_in, b_qkv_in, b_E_in,
                     Qb, Kb, Vb, Eb, flag);
  hipLaunchKernelGGL(attn_kernel, dim3(2048), dim3(256), 0, stream, Qb, Kb, Vb, Eb, mask, Va, 0, flag);

  // out pass
  hipLaunchKernelGGL(qkv_valu, dim3(8192), dim3(256), 0, stream, eln, W_qkv_out, W_E_out, b_qkv_out, b_E_out,
                     Qb, Kb, Vb, Eb, flag);
  hipLaunchKernelGGL(attn_kernel, dim3(2048), dim3(256), 0, stream, Qb, Kb, Vb, Eb, mask, Va, 1, flag);

  hipLaunchKernelGGL(out_valu, dim3(8192), dim3(256), 0, stream, Va, W_O, b_O, out, flag);
}

// Round 7
// 553.727 us; speedup vs baseline: 3.3150x; 3.3150x over previous
//
#include <hip/hip_runtime.h>

// Problem: B=2, N=128, C=256, H=8, D=32. Inputs fp32, OUTPUT fp32 (proven R6).
// R7: MFMA everywhere. Va layout cc' = pass*256+h*32+d (attn-friendly, W_O
// permuted to match in prep_wo). Bias[b][h][i][k] fp32 = E + mask, premerged.
typedef unsigned short u16;
typedef __attribute__((ext_vector_type(8))) short bf16x8;   // 8 bf16 MFMA A/B frag
typedef __attribute__((ext_vector_type(4))) float f32x4;    // MFMA C/D frag

#define SCALE 0.17677669529663687f  // 32^-0.5

__device__ __forceinline__ float us2f(u16 u){ return __uint_as_float(((unsigned int)u)<<16); }
__device__ __forceinline__ u16 f2us(float f){
  unsigned int x = __float_as_uint(f);
  x += 0x7fffu + ((x>>16)&1u);   // RNE
  return (u16)(x>>16);
}

// ---------------- LayerNorm: one wave per token (256 ch), float4 loads ----------------
__global__ __launch_bounds__(256) void ln_kernel(const float* __restrict__ e, const float* __restrict__ g,
                                                 const float* __restrict__ bb, u16* __restrict__ eln){
  int t = threadIdx.x;
  int tok = blockIdx.x*4 + (t>>6);
  int lane = t & 63;
  int c0 = lane*4;
  float4 x = *(const float4*)(e + tok*256 + c0);
  float sum = x.x+x.y+x.z+x.w;
  float sq  = x.x*x.x + x.y*x.y + x.z*x.z + x.w*x.w;
  #pragma unroll
  for (int off=32; off>=1; off>>=1){ sum += __shfl_xor(sum, off); sq += __shfl_xor(sq, off); }
  float mu = sum * 0.00390625f;
  float var = sq * 0.00390625f - mu*mu;
  float rstd = rsqrtf(var + 1e-5f);
  float4 gv = *(const float4*)(g + c0);
  float4 bv = *(const float4*)(bb + c0);
  ushort4 o;
  o.x = f2us((x.x-mu)*rstd*gv.x + bv.x);
  o.y = f2us((x.y-mu)*rstd*gv.y + bv.y);
  o.z = f2us((x.z-mu)*rstd*gv.z + bv.z);
  o.w = f2us((x.w-mu)*rstd*gv.w + bv.w);
  *(ushort4*)(eln + tok*256 + c0) = o;
}

// ---------------- Wt[832][256] = [W_qkv^T ; W_E^T ; 0pad] (bf16) ----------------
__global__ __launch_bounds__(256) void prep_wt(const float* __restrict__ W, const float* __restrict__ WE,
                                               u16* __restrict__ Wt){
  int idx = blockIdx.x*256 + threadIdx.x;   // 832*256
  int n = idx >> 8, k = idx & 255;
  float v;
  if (n < 768) v = W[k*768 + n];
  else if (n < 776) v = WE[k*8 + (n-768)];
  else v = 0.f;
  Wt[idx] = f2us(v);
}

// WOt[256][512] permuted: k' = pass*256+h*32+d  <->  W_O row r = d*16+pass*8+h
__global__ __launch_bounds__(256) void prep_wo(const float* __restrict__ WO, u16* __restrict__ WOt){
  int idx = blockIdx.x*256 + threadIdx.x;   // 131072
  int n = idx >> 9, kp = idx & 511;
  int pass = kp >> 8, h = (kp >> 5) & 7, d = kp & 31;
  int r = d*16 + pass*8 + h;
  WOt[idx] = f2us(WO[r*256 + n]);
}

// ---------------- QKV (+E) GEMM: [32768x256] @ Wt^T, MFMA 16x16x32 ----------------
// E columns written straight into bias[b][h][t_q][t_k] (fp32); mask added later.
__global__ __launch_bounds__(256) void qkv_gemm(const u16* __restrict__ eln, const u16* __restrict__ Wt,
    const float* __restrict__ bqkv, const float* __restrict__ bE,
    u16* __restrict__ Qb, u16* __restrict__ Kb, u16* __restrict__ Vb, float* __restrict__ bias,
    int pass){
  int wid = blockIdx.x*4 + (threadIdx.x>>6);   // 2048*13 waves
  int lane = threadIdx.x & 63;
  int tm = wid/13, g = wid - tm*13;
  int r16 = lane & 15, kq = lane >> 4;
  const bf16x8* Ap = (const bf16x8*)(eln + (tm*16 + r16)*256 + kq*8);
  const bf16x8* Bp[4];
  #pragma unroll
  for (int nt=0; nt<4; ++nt)
    Bp[nt] = (const bf16x8*)(Wt + ((g*4+nt)*16 + r16)*256 + kq*8);
  f32x4 zero = {0.f,0.f,0.f,0.f};
  f32x4 acc[4];
  #pragma unroll
  for (int nt=0; nt<4; ++nt) acc[nt] = zero;
  #pragma unroll
  for (int s=0; s<8; ++s){
    bf16x8 a = Ap[s*4];
    #pragma unroll
    for (int nt=0; nt<4; ++nt)
      acc[nt] = __builtin_amdgcn_mfma_f32_16x16x32_bf16(a, Bp[nt][s*4], acc[nt], 0,0,0);
  }
  #pragma unroll
  for (int nt=0; nt<4; ++nt){
    int col = (g*4+nt)*16 + r16;
    #pragma unroll
    for (int rr=0; rr<4; ++rr){
      int tok = tm*16 + kq*4 + rr;       // C/D: row = (lane>>4)*4 + reg
      float v = acc[nt][rr];
      if (col < 768){
        v += bqkv[col];
        int sec = col >> 8;
        int c = col & 255;
        int off = tok*256 + (c&7)*32 + (c>>3);   // [tok][h][d], c = d*8+h
        if (sec == 0)      Qb[off] = f2us(v * SCALE);
        else if (sec == 1) Kb[off] = f2us(v);
        else               Vb[off] = f2us(v);
      } else if (col < 776){
        int h = col - 768;
        int bb = tok >> 14, t1 = (tok >> 7) & 127, t2 = tok & 127;
        int tq = pass ? t2 : t1, tk = pass ? t1 : t2;
        bias[((bb*8 + h)*128 + tq)*128 + tk] = v + bE[h];
      }
    }
  }
}

// ---------------- add mask into premerged bias ----------------
__global__ __launch_bounds__(256) void mask_add(float* __restrict__ bias, const float* __restrict__ mask,
                                                int pass){
  int idx = blockIdx.x*256 + threadIdx.x;   // 262144
  int k = idx & 127, i = (idx>>7) & 127, h = (idx>>14) & 7, b = idx >> 17;
  int src = pass ? (((b*128+k)*128+i)*8+h) : (((b*128+i)*128+k)*8+h);
  bias[idx] += mask[src];
}

// ---------------- MFMA attention: one block per (b,j,h) ----------------
__global__ __launch_bounds__(256) void attn_mfma(const u16* __restrict__ Qb, const u16* __restrict__ Kb,
    const u16* __restrict__ Vb, const float* __restrict__ bias, u16* __restrict__ Va, int pass){
  __shared__ u16 Qs[128][40];    // 80 B stride: 16B-aligned b128, <=2-way banks
  __shared__ u16 Ks[128][40];
  __shared__ u16 Vs[128][34];    // 17-word stride spreads scalar B-frag reads
  __shared__ u16 Ps[128][136];   // 68-word stride, 16B-aligned b128 A-frag reads
  int t = threadIdx.x;
  int bx = blockIdx.x;
  int h = bx & 7, j = (bx>>3) & 127, b = bx >> 10;

  #pragma unroll
  for (int it2=0; it2<2; ++it2){
    int idx = it2*256 + t;              // 512 chunks of 8 u16
    int row = idx >> 2, seg = idx & 3;
    int qoff  = ((b*128 + row)*128 + j)*256 + h*32 + seg*8;
    int kvtok = (pass == 0) ? ((b*128 + j)*128 + row) : ((b*128 + row)*128 + j);
    int kvoff = kvtok*256 + h*32 + seg*8;
    *(uint4*)&Qs[row][seg*8] = *(const uint4*)(Qb + qoff);
    *(uint4*)&Ks[row][seg*8] = *(const uint4*)(Kb + kvoff);
    uint4 vv = *(const uint4*)(Vb + kvoff);
    const u16* vp = (const u16*)&vv;
    #pragma unroll
    for (int q=0;q<8;++q) Vs[row][seg*8+q] = vp[q];
  }
  __syncthreads();

  int w = t >> 6, lane = t & 63, quad = lane >> 4, l15 = lane & 15;
  // ---- S = Q K^T : wave w owns i-rows [w*32, w*32+32)
  bf16x8 aQ[2];
  #pragma unroll
  for (int it=0; it<2; ++it) aQ[it] = *(const bf16x8*)&Qs[w*32 + it*16 + l15][quad*8];
  f32x4 zero = {0.f,0.f,0.f,0.f};
  f32x4 S[2][8];
  #pragma unroll
  for (int tk=0; tk<8; ++tk){
    bf16x8 bK = *(const bf16x8*)&Ks[tk*16 + l15][quad*8];
    #pragma unroll
    for (int it=0; it<2; ++it)
      S[it][tk] = __builtin_amdgcn_mfma_f32_16x16x32_bf16(aQ[it], bK, zero, 0,0,0);
  }
  // ---- bias + row softmax (C layout: row = quad*4+r, col = tk*16+l15)
  const float* bp = bias + ((b*8 + h)*128)*128;
  float inv[2][4];
  #pragma unroll
  for (int it=0; it<2; ++it){
    #pragma unroll
    for (int r=0; r<4; ++r){
      int i = w*32 + it*16 + quad*4 + r;
      const float* bpi = bp + i*128 + l15;
      float sv[8];
      #pragma unroll
      for (int tk=0; tk<8; ++tk) sv[tk] = S[it][tk][r] + bpi[tk*16];
      float m = sv[0];
      #pragma unroll
      for (int tk=1; tk<8; ++tk) m = fmaxf(m, sv[tk]);
      m = fmaxf(m, __shfl_xor(m,1)); m = fmaxf(m, __shfl_xor(m,2));
      m = fmaxf(m, __shfl_xor(m,4)); m = fmaxf(m, __shfl_xor(m,8));
      float l = 0.f;
      #pragma unroll
      for (int tk=0; tk<8; ++tk){ float p = __expf(sv[tk]-m); sv[tk] = p; l += p; }
      l += __shfl_xor(l,1); l += __shfl_xor(l,2); l += __shfl_xor(l,4); l += __shfl_xor(l,8);
      inv[it][r] = 1.0f / l;
      #pragma unroll
      for (int tk=0; tk<8; ++tk) Ps[i][tk*16 + l15] = f2us(sv[tk]);
    }
  }
  // ---- O = P V : 2 i-tiles x 2 d-tiles, K=128 in 4 chunks of 32
  f32x4 O[2][2];
  #pragma unroll
  for (int it=0; it<2; ++it)
    #pragma unroll
    for (int dt=0; dt<2; ++dt) O[it][dt] = zero;
  #pragma unroll
  for (int kc=0; kc<4; ++kc){
    bf16x8 bV[2];
    #pragma unroll
    for (int dt=0; dt<2; ++dt){
      #pragma unroll
      for (int jj=0; jj<8; ++jj) bV[dt][jj] = (short)Vs[kc*32 + quad*8 + jj][dt*16 + l15];
    }
    #pragma unroll
    for (int it=0; it<2; ++it){
      bf16x8 aP = *(const bf16x8*)&Ps[w*32 + it*16 + l15][kc*32 + quad*8];
      #pragma unroll
      for (int dt=0; dt<2; ++dt)
        O[it][dt] = __builtin_amdgcn_mfma_f32_16x16x32_bf16(aP, bV[dt], O[it][dt], 0,0,0);
    }
  }
  // ---- store Va[tok][pass*256 + h*32 + d]
  #pragma unroll
  for (int it=0; it<2; ++it){
    #pragma unroll
    for (int r=0; r<4; ++r){
      int i = w*32 + it*16 + quad*4 + r;
      int obase = ((b*128 + i)*128 + j)*512 + pass*256 + h*32;
      #pragma unroll
      for (int dt=0; dt<2; ++dt)
        Va[obase + dt*16 + l15] = f2us(O[it][dt][r] * inv[it][r]);
    }
  }
}

// ---------------- Output GEMM: [32768x512] @ WOt^T -> fp32 out ----------------
__global__ __launch_bounds__(256) void out_gemm(const u16* __restrict__ Va, const u16* __restrict__ WOt,
                                                const float* __restrict__ bO, float* __restrict__ out){
  int wid = blockIdx.x*4 + (threadIdx.x>>6);   // 2048*4 waves
  int lane = threadIdx.x & 63;
  int tm = wid >> 2, g = wid & 3;
  int r16 = lane & 15, kq = lane >> 4;
  const bf16x8* Ap = (const bf16x8*)(Va + (tm*16+r16)*512 + kq*8);
  const bf16x8* Bp[4];
  #pragma unroll
  for (int nt=0; nt<4; ++nt)
    Bp[nt] = (const bf16x8*)(WOt + ((g*4+nt)*16 + r16)*512 + kq*8);
  f32x4 zero = {0.f,0.f,0.f,0.f};
  f32x4 acc[4];
  #pragma unroll
  for (int nt=0; nt<4; ++nt) acc[nt] = zero;
  #pragma unroll
  for (int s=0; s<16; ++s){
    bf16x8 a = Ap[s*4];
    #pragma unroll
    for (int nt=0; nt<4; ++nt)
      acc[nt] = __builtin_amdgcn_mfma_f32_16x16x32_bf16(a, Bp[nt][s*4], acc[nt], 0,0,0);
  }
  #pragma unroll
  for (int nt=0; nt<4; ++nt){
    int col = (g*4+nt)*16 + r16;
    float bias = bO[col];
    #pragma unroll
    for (int rr=0; rr<4; ++rr){
      int tok = tm*16 + kq*4 + rr;
      out[tok*256 + col] = acc[nt][rr] + bias;
    }
  }
}

// ---------------- ws layout (bytes), total 102,400,000 (proven-safe envelope) ----------------
#define OFF_ELN  0u            // 32768*256 bf16 = 16,777,216
#define OFF_QB   16777216u
#define OFF_KB   33554432u
#define OFF_VB   50331648u
#define OFF_VA   67108864u     // 32768*512 bf16 = 33,554,432
#define OFF_BIAS 100663296u    // 2*8*128*128 f32 = 1,048,576
#define OFF_WT   101711872u    // 832*256 bf16 = 425,984
#define OFF_WOT  102137856u    // 256*512 bf16 = 262,144  -> end 102,400,000

extern "C" void kernel_launch(void* const* d_in, const int* in_sizes, int n_in,
                              void* d_out, int out_size, void* d_ws, size_t ws_size,
                              hipStream_t stream) {
  (void)in_sizes; (void)n_in; (void)out_size; (void)ws_size;
  const float* e        = (const float*)d_in[0];
  const float* mask     = (const float*)d_in[1];
  const float* ln_g     = (const float*)d_in[2];
  const float* ln_b     = (const float*)d_in[3];
  const float* W_qkv_in = (const float*)d_in[4];
  const float* b_qkv_in = (const float*)d_in[5];
  const float* W_E_in   = (const float*)d_in[6];
  const float* b_E_in   = (const float*)d_in[7];
  const float* W_qkv_out= (const float*)d_in[8];
  const float* b_qkv_out= (const float*)d_in[9];
  const float* W_E_out  = (const float*)d_in[10];
  const float* b_E_out  = (const float*)d_in[11];
  const float* W_O      = (const float*)d_in[12];
  const float* b_O      = (const float*)d_in[13];

  char* ws = (char*)d_ws;
  u16*   eln  = (u16*)(ws + OFF_ELN);
  u16*   Qb   = (u16*)(ws + OFF_QB);
  u16*   Kb   = (u16*)(ws + OFF_KB);
  u16*   Vb   = (u16*)(ws + OFF_VB);
  u16*   Va   = (u16*)(ws + OFF_VA);
  float* bias = (float*)(ws + OFF_BIAS);
  u16*   Wt   = (u16*)(ws + OFF_WT);
  u16*   WOt  = (u16*)(ws + OFF_WOT);

  float* out = (float*)d_out;

  hipLaunchKernelGGL(prep_wo, dim3(512), dim3(256), 0, stream, W_O, WOt);
  hipLaunchKernelGGL(ln_kernel, dim3(8192), dim3(256), 0, stream, e, ln_g, ln_b, eln);

  // in pass
  hipLaunchKernelGGL(prep_wt, dim3(832), dim3(256), 0, stream, W_qkv_in, W_E_in, Wt);
  hipLaunchKernelGGL(qkv_gemm, dim3(6656), dim3(256), 0, stream, eln, Wt, b_qkv_in, b_E_in,
                     Qb, Kb, Vb, bias, 0);
  hipLaunchKernelGGL(mask_add, dim3(1024), dim3(256), 0, stream, bias, mask, 0);
  hipLaunchKernelGGL(attn_mfma, dim3(2048), dim3(256), 0, stream, Qb, Kb, Vb, bias, Va, 0);

  // out pass
  hipLaunchKernelGGL(prep_wt, dim3(832), dim3(256), 0, stream, W_qkv_out, W_E_out, Wt);
  hipLaunchKernelGGL(qkv_gemm, dim3(6656), dim3(256), 0, stream, eln, Wt, b_qkv_out, b_E_out,
                     Qb, Kb, Vb, bias, 1);
  hipLaunchKernelGGL(mask_add, dim3(1024), dim3(256), 0, stream, bias, mask, 1);
  hipLaunchKernelGGL(attn_mfma, dim3(2048), dim3(256), 0, stream, Qb, Kb, Vb, bias, Va, 1);

  hipLaunchKernelGGL(out_gemm, dim3(2048), dim3(256), 0, stream, Va, WOt, b_O, out);
}